// Round 2
// baseline (925.337 us; speedup 1.0000x reference)
//
#include <hip/hip_runtime.h>

#define DIM   64
#define K_CL  512
#define NFLT  (K_CL * 65 + K_CL)   // 33792 floats = 135168 B (max of both phases)

// ---------------------------------------------------------------------------
// Pre-kernel: half squared norms of centers -> ws
// ---------------------------------------------------------------------------
__global__ void c2_kernel(const float* __restrict__ centers,
                          float* __restrict__ halfc2) {
    int k = blockIdx.x * blockDim.x + threadIdx.x;
    if (k < K_CL) {
        const float4* c4 = (const float4*)(centers + k * DIM);
        float s = 0.f;
#pragma unroll
        for (int i = 0; i < DIM / 4; ++i) {
            float4 v = c4[i];
            s += v.x * v.x + v.y * v.y + v.z * v.z + v.w * v.w;
        }
        halfc2[k] = 0.5f * s;
    }
}

// ---------------------------------------------------------------------------
// Fused assign + per-block partial segment-sum.
// 256 blocks x 1024 threads, 2 points/thread (sequential).
// Phase A: centers staged in LDS (128 KB) + hc2 (2 KB); argmin with
//          wave-uniform ds_read_b128 broadcast (in-order -> fine lgkmcnt).
// Phase B: LDS re-zeroed, reused as padded [512][65] partial sums; x
//          re-read (L3-hot) and accumulated via LDS atomics, then flushed
//          with global atomics.
// ---------------------------------------------------------------------------
__global__ __launch_bounds__(1024)
void assign_reduce_kernel(const float* __restrict__ x,
                          const float* __restrict__ centers,
                          const float* __restrict__ halfc2,
                          float* __restrict__ gsums,   // [K_CL*DIM]
                          float* __restrict__ gcnt) {  // [K_CL]
    __shared__ float lds[NFLT];

    // ---- stage centers + hc2 into LDS (coalesced float4) ----
    {
        const float4* c4 = (const float4*)centers;
        float4* l4 = (float4*)lds;
        for (int i = threadIdx.x; i < (K_CL * DIM) / 4; i += 1024) l4[i] = c4[i];
        if (threadIdx.x < K_CL)
            lds[K_CL * DIM + threadIdx.x] = halfc2[threadIdx.x];
    }
    __syncthreads();

    const int pt_base = blockIdx.x * 2048 + threadIdx.x;
    int bidx0 = 0, bidx1 = 0;

    // ---- Phase A: argmin over 512 centers, 2 points sequentially ----
    for (int it = 0; it < 2; ++it) {
        const int p = pt_base + it * 1024;
        const float4* xp = (const float4*)(x + (size_t)p * DIM);
        float4 xr[16];
#pragma unroll
        for (int i = 0; i < 16; ++i) xr[i] = xp[i];

        float best = 3.4e38f;
        int   bi = 0;
#pragma unroll 2
        for (int k = 0; k < K_CL; ++k) {
            const float4* cp = (const float4*)(lds + k * DIM);
            float h = lds[K_CL * DIM + k];   // broadcast ds_read
            float a0 = 0.f, a1 = 0.f, a2 = 0.f, a3 = 0.f;
#pragma unroll
            for (int i = 0; i < 16; ++i) {
                float4 c = cp[i];            // uniform addr -> broadcast ds_read_b128
                a0 = fmaf(xr[i].x, c.x, a0);
                a1 = fmaf(xr[i].y, c.y, a1);
                a2 = fmaf(xr[i].z, c.z, a2);
                a3 = fmaf(xr[i].w, c.w, a3);
            }
            float score = h - ((a0 + a1) + (a2 + a3));
            if (score < best) { best = score; bi = k; }
        }
        if (it == 0) bidx0 = bi; else bidx1 = bi;
    }

    // ---- Phase B: reuse LDS as padded partial sums ----
    __syncthreads();
    for (int i = threadIdx.x; i < NFLT; i += 1024) lds[i] = 0.f;
    __syncthreads();

#pragma unroll
    for (int it = 0; it < 2; ++it) {
        const int p = pt_base + it * 1024;
        const float4* xp = (const float4*)(x + (size_t)p * DIM);
        const int bi = (it == 0) ? bidx0 : bidx1;
        float* dst = lds + bi * 65;          // stride 65: bank = (bi + d) % 32
#pragma unroll
        for (int i = 0; i < 16; ++i) {
            float4 v = xp[i];                // L3-hot re-read
            atomicAdd(&dst[4 * i + 0], v.x);
            atomicAdd(&dst[4 * i + 1], v.y);
            atomicAdd(&dst[4 * i + 2], v.z);
            atomicAdd(&dst[4 * i + 3], v.w);
        }
        atomicAdd(&lds[K_CL * 65 + bi], 1.f);
    }
    __syncthreads();

    // ---- flush block partials to global accumulators ----
    for (int i = threadIdx.x; i < K_CL * DIM; i += 1024) {
        int k = i >> 6, d = i & 63;
        atomicAdd(&gsums[i], lds[k * 65 + d]);
    }
    if (threadIdx.x < K_CL)
        atomicAdd(&gcnt[threadIdx.x], lds[K_CL * 65 + threadIdx.x]);
}

// ---------------------------------------------------------------------------
// Finalize: means (or keep old center when count==0) + counts -> d_out
// ---------------------------------------------------------------------------
__global__ void finalize_kernel(const float* __restrict__ gsums,
                                const float* __restrict__ gcnt,
                                const float* __restrict__ centers,
                                float* __restrict__ out) {
    int i = blockIdx.x * 256 + threadIdx.x;
    if (i < K_CL * DIM) {
        int k = i >> 6;
        float c = gcnt[k];
        out[i] = (c > 0.f) ? (gsums[i] / c) : centers[i];
    } else if (i < K_CL * DIM + K_CL) {
        out[i] = gcnt[i - K_CL * DIM];
    }
}

extern "C" void kernel_launch(void* const* d_in, const int* in_sizes, int n_in,
                              void* d_out, int out_size, void* d_ws, size_t ws_size,
                              hipStream_t stream) {
    const float* x       = (const float*)d_in[0];
    const float* centers = (const float*)d_in[1];

    float* ws    = (float*)d_ws;
    float* gsums = ws;                       // 32768 floats
    float* gcnt  = ws + K_CL * DIM;          // 512 floats
    float* hc2   = ws + K_CL * DIM + K_CL;   // 512 floats

    hipMemsetAsync(ws, 0, (K_CL * DIM + K_CL) * sizeof(float), stream);
    c2_kernel<<<2, 256, 0, stream>>>(centers, hc2);
    assign_reduce_kernel<<<256, 1024, 0, stream>>>(x, centers, hc2, gsums, gcnt);
    finalize_kernel<<<(K_CL * DIM + K_CL + 255) / 256, 256, 0, stream>>>(
        gsums, gcnt, centers, (float*)d_out);
}

// Round 3
// 425.330 us; speedup vs baseline: 2.1756x; 2.1756x over previous
//
#include <hip/hip_runtime.h>

typedef __attribute__((ext_vector_type(8)))  short short8;
typedef __attribute__((ext_vector_type(16))) float f32x16;

#define N_PTS 524288
#define DIM   64
#define K_CL  512

// ---------------------------------------------------------------------------
// prep: hc2[k] = 0.5*||c_k||^2 ; chi/clo = bf16 hi/lo split of NEGATED centers
// ---------------------------------------------------------------------------
__global__ void prep_kernel(const float* __restrict__ c,
                            unsigned short* __restrict__ chi,
                            unsigned short* __restrict__ clo,
                            float* __restrict__ hc2) {
    int k = blockIdx.x * blockDim.x + threadIdx.x;
    if (k >= K_CL) return;
    float s = 0.f;
    for (int d = 0; d < DIM; ++d) {
        float v = c[k * DIM + d];
        s += v * v;
        float nv = -v;
        unsigned int u  = __builtin_bit_cast(unsigned int, nv);
        unsigned int hr = (u + 0x7FFFu + ((u >> 16) & 1u)) & 0xFFFF0000u;
        chi[k * DIM + d] = (unsigned short)(hr >> 16);
        float lo = nv - __builtin_bit_cast(float, hr);
        unsigned int ul = __builtin_bit_cast(unsigned int, lo);
        unsigned int lr = ul + 0x7FFFu + ((ul >> 16) & 1u);
        clo[k * DIM + d] = (unsigned short)(lr >> 16);
    }
    hc2[k] = 0.5f * s;
}

// split 8 fp32 (two float4) into bf16 hi + lo fragments (RNE)
__device__ inline void split8(float4 a, float4 b, short8& hi, short8& lo) {
    float fa[8] = {a.x, a.y, a.z, a.w, b.x, b.y, b.z, b.w};
    short8 H, L;
#pragma unroll
    for (int j = 0; j < 8; ++j) {
        unsigned int u  = __builtin_bit_cast(unsigned int, fa[j]);
        unsigned int hr = (u + 0x7FFFu + ((u >> 16) & 1u)) & 0xFFFF0000u;
        H[j] = (short)(hr >> 16);
        float lof = fa[j] - __builtin_bit_cast(float, hr);
        unsigned int ul = __builtin_bit_cast(unsigned int, lof);
        unsigned int lr = ul + 0x7FFFu + ((ul >> 16) & 1u);
        L[j] = (short)(lr >> 16);
    }
    hi = H; lo = L;
}

// ---------------------------------------------------------------------------
// assign: 8 waves x 64 centers resident in VGPRs; 16 tiles of 32 points/block.
// D = C_neg * X^T via mfma_f32_32x32x16_bf16 (3 hi/lo products, K=64).
// Lane l holds point (l&31), centers rows (reg&3)+8*(reg>>2)+4*(l>>5).
// ---------------------------------------------------------------------------
__global__ __launch_bounds__(512, 3)
void assign_kernel(const float* __restrict__ x,
                   const unsigned short* __restrict__ chi_g,
                   const unsigned short* __restrict__ clo_g,
                   const float* __restrict__ hc2g,
                   unsigned int* __restrict__ assign) {
    __shared__ float lds_hc2[K_CL];
    __shared__ unsigned int lds_red[8][32][2];

    const int tid  = threadIdx.x;
    const int wave = tid >> 6;
    const int lane = tid & 63;
    const int l31  = lane & 31;
    const int h    = lane >> 5;

    if (tid < K_CL) lds_hc2[tid] = hc2g[tid];

    // resident center fragments: [ct][ks], hi and lo
    short8 cH[2][4], cL[2][4];
#pragma unroll
    for (int ct = 0; ct < 2; ++ct) {
        int row = wave * 64 + ct * 32 + l31;
#pragma unroll
        for (int ks = 0; ks < 4; ++ks) {
            size_t off = (size_t)row * DIM + ks * 16 + h * 8;
            cH[ct][ks] = *(const short8*)(chi_g + off);
            cL[ct][ks] = *(const short8*)(clo_g + off);
        }
    }
    __syncthreads();

    const int tile0 = blockIdx.x * 16;
    for (int t = 0; t < 16; ++t) {
        const int tb = (tile0 + t) * 32;

        // X fragment source: 8 consecutive fp32 per lane
        float4 xf[4][2];
#pragma unroll
        for (int ks = 0; ks < 4; ++ks) {
            const float* p = x + (size_t)(tb + l31) * DIM + ks * 16 + h * 8;
            xf[ks][0] = *(const float4*)(p);
            xf[ks][1] = *(const float4*)(p + 4);
        }

        // acc init = hc2 bias per center row
        f32x16 acc0, acc1;
#pragma unroll
        for (int g = 0; g < 4; ++g) {
            float4 b0 = *(const float4*)&lds_hc2[wave * 64 + 0  + 8 * g + 4 * h];
            float4 b1 = *(const float4*)&lds_hc2[wave * 64 + 32 + 8 * g + 4 * h];
            acc0[4*g+0] = b0.x; acc0[4*g+1] = b0.y; acc0[4*g+2] = b0.z; acc0[4*g+3] = b0.w;
            acc1[4*g+0] = b1.x; acc1[4*g+1] = b1.y; acc1[4*g+2] = b1.z; acc1[4*g+3] = b1.w;
        }

#pragma unroll
        for (int ks = 0; ks < 4; ++ks) {
            short8 xh, xl;
            split8(xf[ks][0], xf[ks][1], xh, xl);
            acc0 = __builtin_amdgcn_mfma_f32_32x32x16_bf16(cH[0][ks], xh, acc0, 0, 0, 0);
            acc1 = __builtin_amdgcn_mfma_f32_32x32x16_bf16(cH[1][ks], xh, acc1, 0, 0, 0);
            acc0 = __builtin_amdgcn_mfma_f32_32x32x16_bf16(cH[0][ks], xl, acc0, 0, 0, 0);
            acc1 = __builtin_amdgcn_mfma_f32_32x32x16_bf16(cH[1][ks], xl, acc1, 0, 0, 0);
            acc0 = __builtin_amdgcn_mfma_f32_32x32x16_bf16(cL[0][ks], xh, acc0, 0, 0, 0);
            acc1 = __builtin_amdgcn_mfma_f32_32x32x16_bf16(cL[1][ks], xh, acc1, 0, 0, 0);
        }

        // in-lane argmin (ascending center id, strict < => first-occurrence)
        float bv = acc0[0];
        int   bi = wave * 64 + 4 * h;
#pragma unroll
        for (int r = 1; r < 16; ++r) {
            int id = wave * 64 + ((r & 3) + 8 * (r >> 2)) + 4 * h;
            float v = acc0[r];
            if (v < bv) { bv = v; bi = id; }
        }
#pragma unroll
        for (int r = 0; r < 16; ++r) {
            int id = wave * 64 + 32 + ((r & 3) + 8 * (r >> 2)) + 4 * h;
            float v = acc1[r];
            if (v < bv) { bv = v; bi = id; }
        }
        // combine the two lane-halves (same point)
        float ov = __shfl_xor(bv, 32, 64);
        int   oi = __shfl_xor(bi, 32, 64);
        if (ov < bv || (ov == bv && oi < bi)) { bv = ov; bi = oi; }

        if (lane < 32) {
            lds_red[wave][l31][0] = __builtin_bit_cast(unsigned int, bv);
            lds_red[wave][l31][1] = (unsigned int)bi;
        }
        __syncthreads();
        if (tid < 32) {
            float        fv = __builtin_bit_cast(float, lds_red[0][tid][0]);
            unsigned int fi = lds_red[0][tid][1];
#pragma unroll
            for (int w2 = 1; w2 < 8; ++w2) {
                float        v  = __builtin_bit_cast(float, lds_red[w2][tid][0]);
                unsigned int i2 = lds_red[w2][tid][1];
                if (v < fv) { fv = v; fi = i2; }
            }
            assign[tb + tid] = fi;
        }
        __syncthreads();
    }
}

// ---------------------------------------------------------------------------
// reduce: LDS partial segment sums (padded stride 65) + global atomic flush
// ---------------------------------------------------------------------------
__global__ __launch_bounds__(1024)
void reduce_kernel(const float* __restrict__ x,
                   const unsigned int* __restrict__ assign,
                   float* __restrict__ gsums, float* __restrict__ gcnt) {
    __shared__ float lds[K_CL * 65 + K_CL];
    for (int i = threadIdx.x; i < K_CL * 65 + K_CL; i += 1024) lds[i] = 0.f;
    __syncthreads();

    const int pt_base = blockIdx.x * 2048 + threadIdx.x;
#pragma unroll
    for (int it = 0; it < 2; ++it) {
        int p = pt_base + it * 1024;
        const float4* xp = (const float4*)(x + (size_t)p * DIM);
        int a = assign[p];
        float* dst = lds + a * 65;
#pragma unroll
        for (int i = 0; i < 16; ++i) {
            float4 v = xp[i];
            atomicAdd(&dst[4 * i + 0], v.x);
            atomicAdd(&dst[4 * i + 1], v.y);
            atomicAdd(&dst[4 * i + 2], v.z);
            atomicAdd(&dst[4 * i + 3], v.w);
        }
        atomicAdd(&lds[K_CL * 65 + a], 1.f);
    }
    __syncthreads();

    for (int i = threadIdx.x; i < K_CL * DIM; i += 1024) {
        int k = i >> 6, d = i & 63;
        atomicAdd(&gsums[i], lds[k * 65 + d]);
    }
    if (threadIdx.x < K_CL)
        atomicAdd(&gcnt[threadIdx.x], lds[K_CL * 65 + threadIdx.x]);
}

__global__ void finalize_kernel(const float* __restrict__ gsums,
                                const float* __restrict__ gcnt,
                                const float* __restrict__ centers,
                                float* __restrict__ out) {
    int i = blockIdx.x * 256 + threadIdx.x;
    if (i < K_CL * DIM) {
        int k = i >> 6;
        float c = gcnt[k];
        out[i] = (c > 0.f) ? (gsums[i] / c) : centers[i];
    } else if (i < K_CL * DIM + K_CL) {
        out[i] = gcnt[i - K_CL * DIM];
    }
}

extern "C" void kernel_launch(void* const* d_in, const int* in_sizes, int n_in,
                              void* d_out, int out_size, void* d_ws, size_t ws_size,
                              hipStream_t stream) {
    const float* x       = (const float*)d_in[0];
    const float* centers = (const float*)d_in[1];

    char* ws = (char*)d_ws;
    unsigned short* chi    = (unsigned short*)(ws);            // 64 KiB
    unsigned short* clo    = (unsigned short*)(ws + 65536);    // 64 KiB
    float*          hc2    = (float*)(ws + 131072);            // 2 KiB
    float*          gsums  = (float*)(ws + 133120);            // 128 KiB
    float*          gcnt   = (float*)(ws + 264192);            // 2 KiB
    unsigned int*   assign = (unsigned int*)(ws + 266240);     // 2 MiB

    hipMemsetAsync(ws + 133120, 0, 133120, stream);  // gsums + gcnt
    prep_kernel<<<8, 64, 0, stream>>>(centers, chi, clo, hc2);
    assign_kernel<<<1024, 512, 0, stream>>>(x, chi, clo, hc2, assign);
    reduce_kernel<<<256, 1024, 0, stream>>>(x, assign, gsums, gcnt);
    finalize_kernel<<<(K_CL * DIM + K_CL + 255) / 256, 256, 0, stream>>>(
        gsums, gcnt, centers, (float*)d_out);
}